// Round 13
// baseline (698.077 us; speedup 1.0000x reference)
//
#include <hip/hip_runtime.h>
#include <math.h>

#define TT 65536
#define DD 256
#define EE 8
#define HH 512
#define OO 256
#define NN 4096

typedef unsigned int u32;
typedef unsigned short u16;
typedef __attribute__((ext_vector_type(4))) float f32x4;
typedef __attribute__((ext_vector_type(16))) float f32x16;
typedef __attribute__((ext_vector_type(2))) u32 u32x2;
typedef __attribute__((ext_vector_type(4))) u32 u32x4;
typedef __attribute__((ext_vector_type(8))) __bf16 bf16x8;

__device__ __forceinline__ u16 f2bf(float f) {
    u32 u = __builtin_bit_cast(u32, f);
    u32 r = (u + 0x7fffu + ((u >> 16) & 1u)) >> 16;
    return (u16)r;
}

__device__ __forceinline__ u32 cvt_pk_bf16(float lo, float hi) {
    u32 r;
    asm("v_cvt_pk_bf16_f32 %0, %1, %2" : "=v"(r) : "v"(lo), "v"(hi));
    return r;
}

__device__ __forceinline__ bf16x8 ld_frag(const void* p) {
    u32x4 v = *(const u32x4*)p;
    return __builtin_bit_cast(bf16x8, v);
}

__device__ __forceinline__ float gelu_fast(float v) {
    float t = v * v;
    float u = __builtin_fmaf(t, -0.1029479f, -2.3022075f);
    float z = v * u;
    float e = __builtin_amdgcn_exp2f(z);
    return v * __builtin_amdgcn_rcpf(1.0f + e);
}

// ---------------- weight conversions to fragment-major layout ----------------
// w1 [E][D][H] f32 -> w1s [nb=n>>5][kb=k>>4][l=n&31][j=k&15] bf16 (n=e*512+h, k=d)
__global__ __launch_bounds__(256) void k_conv_w1(const float* __restrict__ w1, u16* __restrict__ w1s) {
    int i = blockIdx.x * 256 + threadIdx.x;            // < 1M
    int j = i & 15, l = (i >> 4) & 31, kb = (i >> 9) & 15, nb = i >> 13;
    int n = nb * 32 + l, k = kb * 16 + j;
    int e = n >> 9, h = n & 511;
    w1s[i] = f2bf(w1[(size_t)e * 131072 + (size_t)k * 512 + h]);
}
// w2 [E][H][O] f32 -> w2s [ob=o>>5][kb2=k2>>4][l=o&31][j=k2&15] bf16 (k2=e*512+h)
__global__ __launch_bounds__(256) void k_conv_w2(const float* __restrict__ w2, u16* __restrict__ w2s) {
    int i = blockIdx.x * 256 + threadIdx.x;            // < 1M
    int j = i & 15, l = (i >> 4) & 31, kb2 = (i >> 9) & 255, ob = i >> 17;
    int o = ob * 32 + l, k2 = kb2 * 16 + j;
    int e = k2 >> 9, h = k2 & 511;
    w2s[i] = f2bf(w2[(size_t)e * 131072 + (size_t)h * 256 + o]);
}

// ---------------- gating ----------------
__global__ __launch_bounds__(256) void k_gating(const float* __restrict__ x,
                                                const float* __restrict__ gw,
                                                const float* __restrict__ gb,
                                                float* __restrict__ wt,
                                                double* __restrict__ part) {
    __shared__ float gws[DD * EE];
    __shared__ float gbs[EE];
    __shared__ double red[256];
    int tid = threadIdx.x;
    for (int i = tid; i < DD * EE; i += 256) gws[i] = gw[i];
    if (tid < EE) gbs[tid] = gb[tid];
    __syncthreads();

    int t = blockIdx.x * 256 + tid;
    double l[EE];
#pragma unroll
    for (int e = 0; e < EE; ++e) l[e] = (double)gbs[e];

    const f32x4* xr = (const f32x4*)(x + (size_t)t * DD);
    for (int d4 = 0; d4 < DD / 4; ++d4) {
        f32x4 xv = xr[d4];
#pragma unroll
        for (int j = 0; j < 4; ++j) {
            double xs = (double)xv[j];
            int d = d4 * 4 + j;
#pragma unroll
            for (int e = 0; e < EE; ++e) l[e] += xs * (double)gws[d * EE + e];
        }
    }
    double mx = l[0];
#pragma unroll
    for (int e = 1; e < EE; ++e) mx = l[e] > mx ? l[e] : mx;
    double p[EE], s = 0.0;
#pragma unroll
    for (int e = 0; e < EE; ++e) { p[e] = exp(l[e] - mx); s += p[e]; }
    double inv = 1.0 / s;
    double ent = 0.0;
#pragma unroll
    for (int e = 0; e < EE; ++e) { p[e] *= inv; ent += p[e] * log(p[e] + 1e-8); }

    bool mask[EE];
#pragma unroll
    for (int e = 0; e < EE; ++e) {
        double c = 0.0; int rk = 0;
#pragma unroll
        for (int f = 0; f < EE; ++f) {
            bool before = (p[f] > p[e]) || (p[f] == p[e] && f < e);
            if (before) { c += p[f]; rk++; }
        }
        c += p[e];
        mask[e] = (c <= 0.7) || (rk == 0);
    }
    double ms = 0.0;
#pragma unroll
    for (int e = 0; e < EE; ++e) if (mask[e]) ms += p[e];
    double inv2 = 1.0 / ms;
#pragma unroll
    for (int e = 0; e < EE; ++e) wt[(size_t)e * TT + t] = (float)(mask[e] ? p[e] * inv2 : 0.0);

    red[tid] = -ent;
    __syncthreads();
    for (int st = 128; st > 0; st >>= 1) {
        if (tid < st) red[tid] += red[tid + st];
        __syncthreads();
    }
    if (tid == 0) part[blockIdx.x] = red[0];
}

__global__ __launch_bounds__(256) void k_final(const double* __restrict__ part, float* __restrict__ loss) {
    __shared__ double red[256];
    int tid = threadIdx.x;
    red[tid] = part[tid];
    __syncthreads();
    for (int st = 128; st > 0; st >>= 1) {
        if (tid < st) red[tid] += red[tid + st];
        __syncthreads();
    }
    if (tid == 0) loss[0] = (float)(red[0] / (double)TT);
}

// ---------------- fused MoE MLP (v13: 256 thr, 3 blocks/CU, G2 at 2:1) ----------------
// 64 tok/block, 256 thr (4 waves). 32 chunks of 128 h (e = c>>2). Hs single buffer,
// two barriers per chunk: { G1(c) -> Hs ; BAR ; G2(c) ; BAR }.
// G1: wave = unique 32h strip (wid) x 64tok: hf[2] (32 acc). Per ks: 1 glb A + 2 LDS B -> 2 MFMA.
// G2: wave = unique 64o strip (wid) x 64tok: oacc[2][2] (64 acc). Per ks: 2 glb B + 2 LDS A -> 4 MFMA (2:1).
// Acc = 96; at 3 waves/SIMD unified cap 170 -> VGPR budget ~74. LDS 50K -> 3 blocks/CU.
__global__ __launch_bounds__(256, 3) void k_moe(const float* __restrict__ x,
                                                const u16* __restrict__ w1s,
                                                const u16* __restrict__ w2s,
                                                const float* __restrict__ b1,
                                                const float* __restrict__ b2,
                                                const float* __restrict__ wtg,
                                                float* __restrict__ out) {
    __shared__ __align__(16) unsigned char smem[51200];
    unsigned char* Hs = smem + 32768;                  // 64 rows x 256B (bf16, swizzled)
    float* wts = (float*)(smem + 49152);               // [E][64]

    const int tid = threadIdx.x;
    const int wid = tid >> 6;                          // 0..3
    const int lane = tid & 63;
    const int l31 = lane & 31;
    const int lg2 = lane >> 5;
    const int t0 = blockIdx.x * 64;
    const int lfrag = l31 * 16 + lg2 * 8;              // elems into 512-elem frag

    // stage Xs: 64 rows x 512B bf16, swizzle ^((row&15)<<4)
    {
        const float* xb = x + (size_t)t0 * DD;
#pragma unroll
        for (int i = 0; i < 8; ++i) {
            int L = i * 4096 + tid * 16;
            int row = L >> 9, elem = (L & 511) >> 1;
            const float* src = xb + (size_t)row * DD + elem;
            f32x4 a = *(const f32x4*)src;
            f32x4 b = *(const f32x4*)(src + 4);
            u32x4 o;
            o.x = cvt_pk_bf16(a[0], a[1]); o.y = cvt_pk_bf16(a[2], a[3]);
            o.z = cvt_pk_bf16(b[0], b[1]); o.w = cvt_pk_bf16(b[2], b[3]);
            *(u32x4*)(smem + (L ^ ((row & 15) << 4))) = o;
        }
    }
    wts[tid] = wtg[(size_t)(tid >> 6) * TT + t0 + (tid & 63)];
    wts[tid + 256] = wtg[(size_t)((tid + 256) >> 6) * TT + t0 + (tid & 63)];
    __syncthreads();

    f32x16 oacc[2][2];
#pragma unroll
    for (int m = 0; m < 2; ++m)
#pragma unroll
        for (int n = 0; n < 2; ++n) oacc[m][n] = (f32x16)0.0f;

    // lane addressing constants
    const int tokA = l31, tokB = 32 + l31;
    const int xbA = tokA * 512 + lg2 * 16, rszA = (tokA & 15) << 4;   // Xs rows 512B
    const int xbB = tokB * 512 + lg2 * 16, rszB = (tokB & 15) << 4;
    const int hbA = tokA * 256 + lg2 * 16;                            // Hs rows 256B
    const int hbB = tokB * 256 + lg2 * 16;

#pragma unroll 1
    for (int c = 0; c < 32; ++c) {
        const int e = c >> 2;
        // ---- G1: hf[t] = W1[strip wid, 32h] x X[64 tok], K=256 (16 ks), depth-4 ring
        {
            f32x16 hf0 = (f32x16)0.0f, hf1 = (f32x16)0.0f;
            const u16* w1p = w1s + ((size_t)((c * 4 + wid) * 16)) * 512 + lfrag;
            bf16x8 A[4];
            A[0] = ld_frag(w1p);
            A[1] = ld_frag(w1p + 512);
            A[2] = ld_frag(w1p + 1024);
            A[3] = ld_frag(w1p + 1536);
#pragma unroll 4
            for (int ks = 0; ks < 16; ++ks) {
                bf16x8 ac = A[ks & 3];
                if (ks < 12) A[ks & 3] = ld_frag(w1p + (ks + 4) * 512);
                bf16x8 b0 = ld_frag(smem + ((xbA + ks * 32) ^ rszA));
                bf16x8 b1 = ld_frag(smem + ((xbB + ks * 32) ^ rszB));
                hf0 = __builtin_amdgcn_mfma_f32_32x32x16_bf16(ac, b0, hf0, 0, 0, 0);
                hf1 = __builtin_amdgcn_mfma_f32_32x32x16_bf16(ac, b1, hf1, 0, 0, 0);
            }
            // epilogue: +b1, gelu, *wgt, pack -> Hs (rows tok, 256B, swizzled); h-cols wid*32..+32
            const float* b1p = b1 + c * 128 + wid * 32 + lg2 * 4;
            float wgtA = wts[e * 64 + tokA];
            float wgtB = wts[e * 64 + tokB];
#pragma unroll
            for (int q = 0; q < 4; ++q) {
                f32x4 bb = *(const f32x4*)(b1p + q * 8);
                float g0[4], g1[4];
#pragma unroll
                for (int r = 0; r < 4; ++r) {
                    g0[r] = gelu_fast(hf0[q * 4 + r] + bb[r]) * wgtA;
                    g1[r] = gelu_fast(hf1[q * 4 + r] + bb[r]) * wgtB;
                }
                u32x2 pk0, pk1;
                pk0.x = cvt_pk_bf16(g0[0], g0[1]); pk0.y = cvt_pk_bf16(g0[2], g0[3]);
                pk1.x = cvt_pk_bf16(g1[0], g1[1]); pk1.y = cvt_pk_bf16(g1[2], g1[3]);
                int hb = (wid * 32 + q * 8 + lg2 * 4) * 2;   // byte offset of h within 256B row
                *(u32x2*)(Hs + ((tokA * 256 + hb) ^ rszA)) = pk0;
                *(u32x2*)(Hs + ((tokB * 256 + hb) ^ rszB)) = pk1;
            }
        }
        __syncthreads();
        // ---- G2: oacc[m][n] += Hs[64 tok] x W2[strip wid, 64o], K=128 (8 ks), 2:1
        {
            const u16* w2p0 = w2s + ((size_t)(wid * 2) * 256 + c * 8) * 512 + lfrag;
            const u16* w2p1 = w2p0 + (size_t)256 * 512;
            bf16x8 B0[2], B1[2];
            B0[0] = ld_frag(w2p0);
            B1[0] = ld_frag(w2p1);
            B0[1] = ld_frag(w2p0 + 512);
            B1[1] = ld_frag(w2p1 + 512);
#pragma unroll 4
            for (int ks = 0; ks < 8; ++ks) {
                bf16x8 bc0 = B0[ks & 1], bc1 = B1[ks & 1];
                if (ks < 6) {
                    B0[ks & 1] = ld_frag(w2p0 + (ks + 2) * 512);
                    B1[ks & 1] = ld_frag(w2p1 + (ks + 2) * 512);
                }
                bf16x8 A0 = ld_frag(Hs + ((hbA + ks * 32) ^ rszA));
                bf16x8 A1 = ld_frag(Hs + ((hbB + ks * 32) ^ rszB));
                oacc[0][0] = __builtin_amdgcn_mfma_f32_32x32x16_bf16(A0, bc0, oacc[0][0], 0, 0, 0);
                oacc[0][1] = __builtin_amdgcn_mfma_f32_32x32x16_bf16(A0, bc1, oacc[0][1], 0, 0, 0);
                oacc[1][0] = __builtin_amdgcn_mfma_f32_32x32x16_bf16(A1, bc0, oacc[1][0], 0, 0, 0);
                oacc[1][1] = __builtin_amdgcn_mfma_f32_32x32x16_bf16(A1, bc1, oacc[1][1], 0, 0, 0);
            }
        }
        __syncthreads();
    }

    // epilogue: add sum_e wts[e][tok]*b2[e][o], store. o = wid*64 + n*32 + l31.
#pragma unroll
    for (int n = 0; n < 2; ++n) {
        int o = wid * 64 + n * 32 + l31;
        float b2v[EE];
#pragma unroll
        for (int e = 0; e < EE; ++e) b2v[e] = b2[e * OO + o];
#pragma unroll
        for (int m = 0; m < 2; ++m) {
#pragma unroll
            for (int r = 0; r < 16; ++r) {
                int tok = m * 32 + (r & 3) + 8 * (r >> 2) + 4 * lg2;
                float wb = 0.f;
#pragma unroll
                for (int e = 0; e < EE; ++e) wb += wts[e * 64 + tok] * b2v[e];
                out[(size_t)(t0 + tok) * OO + o] = oacc[m][n][r] + wb;
            }
        }
    }
}

extern "C" void kernel_launch(void* const* d_in, const int* in_sizes, int n_in,
                              void* d_out, int out_size, void* d_ws, size_t ws_size,
                              hipStream_t stream) {
    const float* x  = (const float*)d_in[0];
    const float* gw = (const float*)d_in[1];
    const float* gb = (const float*)d_in[2];
    const float* w1 = (const float*)d_in[3];
    const float* b1 = (const float*)d_in[4];
    const float* w2 = (const float*)d_in[5];
    const float* b2 = (const float*)d_in[6];
    float* out = (float*)d_out;

    char* ws = (char*)d_ws;
    u16* w1s    = (u16*)(ws);                    // 2 MB
    u16* w2s    = (u16*)(ws + 2097152);          // 2 MB
    float* wt   = (float*)(ws + 4194304);        // 2 MB ([E][T])
    double* prt = (double*)(ws + 6291456);       // 2 KB

    k_conv_w1<<<(EE * HH * DD) / 256, 256, 0, stream>>>(w1, w1s);
    k_conv_w2<<<(OO * NN) / 256, 256, 0, stream>>>(w2, w2s);
    k_gating<<<TT / 256, 256, 0, stream>>>(x, gw, gb, wt, prt);
    k_moe<<<TT / 64, 256, 0, stream>>>(x, w1s, w2s, b1, b2, wt, out);
    k_final<<<1, 256, 0, stream>>>(prt, out + (size_t)TT * OO);
}

// Round 14
// 478.539 us; speedup vs baseline: 1.4588x; 1.4588x over previous
//
#include <hip/hip_runtime.h>
#include <math.h>

#define TT 65536
#define DD 256
#define EE 8
#define HH 512
#define OO 256
#define NN 4096

typedef unsigned int u32;
typedef unsigned short u16;
typedef __attribute__((ext_vector_type(4))) float f32x4;
typedef __attribute__((ext_vector_type(16))) float f32x16;
typedef __attribute__((ext_vector_type(2))) u32 u32x2;
typedef __attribute__((ext_vector_type(4))) u32 u32x4;
typedef __attribute__((ext_vector_type(8))) __bf16 bf16x8;

__device__ __forceinline__ u16 f2bf(float f) {
    u32 u = __builtin_bit_cast(u32, f);
    u32 r = (u + 0x7fffu + ((u >> 16) & 1u)) >> 16;
    return (u16)r;
}

__device__ __forceinline__ u32 cvt_pk_bf16(float lo, float hi) {
    u32 r;
    asm("v_cvt_pk_bf16_f32 %0, %1, %2" : "=v"(r) : "v"(lo), "v"(hi));
    return r;
}

__device__ __forceinline__ bf16x8 ld_frag(const void* p) {
    u32x4 v = *(const u32x4*)p;
    return __builtin_bit_cast(bf16x8, v);
}

__device__ __forceinline__ float gelu_fast(float v) {
    float t = v * v;
    float u = __builtin_fmaf(t, -0.1029479f, -2.3022075f);
    float z = v * u;
    float e = __builtin_amdgcn_exp2f(z);
    return v * __builtin_amdgcn_rcpf(1.0f + e);
}

// ---------------- weight conversions to fragment-major layout ----------------
// w1 [E][D][H] f32 -> w1s [nb=n>>5][kb=k>>4][l=n&31][j=k&15] bf16 (n=e*512+h, k=d)
__global__ __launch_bounds__(256) void k_conv_w1(const float* __restrict__ w1, u16* __restrict__ w1s) {
    int i = blockIdx.x * 256 + threadIdx.x;            // < 1M
    int j = i & 15, l = (i >> 4) & 31, kb = (i >> 9) & 15, nb = i >> 13;
    int n = nb * 32 + l, k = kb * 16 + j;
    int e = n >> 9, h = n & 511;
    w1s[i] = f2bf(w1[(size_t)e * 131072 + (size_t)k * 512 + h]);
}
// w2 [E][H][O] f32 -> w2s [ob=o>>5][kb2=k2>>4][l=o&31][j=k2&15] bf16 (k2=e*512+h)
__global__ __launch_bounds__(256) void k_conv_w2(const float* __restrict__ w2, u16* __restrict__ w2s) {
    int i = blockIdx.x * 256 + threadIdx.x;            // < 1M
    int j = i & 15, l = (i >> 4) & 31, kb2 = (i >> 9) & 255, ob = i >> 17;
    int o = ob * 32 + l, k2 = kb2 * 16 + j;
    int e = k2 >> 9, h = k2 & 511;
    w2s[i] = f2bf(w2[(size_t)e * 131072 + (size_t)h * 256 + o]);
}

// ---------------- gating ----------------
__global__ __launch_bounds__(256) void k_gating(const float* __restrict__ x,
                                                const float* __restrict__ gw,
                                                const float* __restrict__ gb,
                                                float* __restrict__ wt,
                                                double* __restrict__ part) {
    __shared__ float gws[DD * EE];
    __shared__ float gbs[EE];
    __shared__ double red[256];
    int tid = threadIdx.x;
    for (int i = tid; i < DD * EE; i += 256) gws[i] = gw[i];
    if (tid < EE) gbs[tid] = gb[tid];
    __syncthreads();

    int t = blockIdx.x * 256 + tid;
    double l[EE];
#pragma unroll
    for (int e = 0; e < EE; ++e) l[e] = (double)gbs[e];

    const f32x4* xr = (const f32x4*)(x + (size_t)t * DD);
    for (int d4 = 0; d4 < DD / 4; ++d4) {
        f32x4 xv = xr[d4];
#pragma unroll
        for (int j = 0; j < 4; ++j) {
            double xs = (double)xv[j];
            int d = d4 * 4 + j;
#pragma unroll
            for (int e = 0; e < EE; ++e) l[e] += xs * (double)gws[d * EE + e];
        }
    }
    double mx = l[0];
#pragma unroll
    for (int e = 1; e < EE; ++e) mx = l[e] > mx ? l[e] : mx;
    double p[EE], s = 0.0;
#pragma unroll
    for (int e = 0; e < EE; ++e) { p[e] = exp(l[e] - mx); s += p[e]; }
    double inv = 1.0 / s;
    double ent = 0.0;
#pragma unroll
    for (int e = 0; e < EE; ++e) { p[e] *= inv; ent += p[e] * log(p[e] + 1e-8); }

    bool mask[EE];
#pragma unroll
    for (int e = 0; e < EE; ++e) {
        double c = 0.0; int rk = 0;
#pragma unroll
        for (int f = 0; f < EE; ++f) {
            bool before = (p[f] > p[e]) || (p[f] == p[e] && f < e);
            if (before) { c += p[f]; rk++; }
        }
        c += p[e];
        mask[e] = (c <= 0.7) || (rk == 0);
    }
    double ms = 0.0;
#pragma unroll
    for (int e = 0; e < EE; ++e) if (mask[e]) ms += p[e];
    double inv2 = 1.0 / ms;
#pragma unroll
    for (int e = 0; e < EE; ++e) wt[(size_t)e * TT + t] = (float)(mask[e] ? p[e] * inv2 : 0.0);

    red[tid] = -ent;
    __syncthreads();
    for (int st = 128; st > 0; st >>= 1) {
        if (tid < st) red[tid] += red[tid + st];
        __syncthreads();
    }
    if (tid == 0) part[blockIdx.x] = red[0];
}

__global__ __launch_bounds__(256) void k_final(const double* __restrict__ part, float* __restrict__ loss) {
    __shared__ double red[256];
    int tid = threadIdx.x;
    red[tid] = part[tid];
    __syncthreads();
    for (int st = 128; st > 0; st >>= 1) {
        if (tid < st) red[tid] += red[tid + st];
        __syncthreads();
    }
    if (tid == 0) loss[0] = (float)(red[0] / (double)TT);
}

// ---------------- fused MoE MLP (v14: K-paired weight tiles, 1 LDS read per 2 MFMA) ----------------
// 64 tok/block, 512 thr (8 waves). 16 chunks of 256 h (e = c>>1). Hs single buffer,
// two barriers per chunk: { G1(c) -> Hs ; BAR ; G2(c) ; BAR }.
// Wave roles: tg = wid&1 (32-tok group), strip = wid>>1 (G1: 64h strip; G2: 64o strip).
// G1: wave = 64h x 32tok: hf0,hf1 (32 acc). Per ks: 2 glb W1 + 1 LDS X -> 2 MFMA.
// G2: wave = 32tok x 64o: oacc[2] (32 acc). Per ks: 2 glb W2 + 1 LDS H -> 2 MFMA.
// W1/W2 read twice per block (once per tok-group) - L2-resident. LDS b128 reads halved vs v12.
// Acc = 64, VGPR ~64 -> unified 128 -> 4 waves/SIMD (2 blocks/CU). LDS 66K.
__global__ __launch_bounds__(512, 4) void k_moe(const float* __restrict__ x,
                                                const u16* __restrict__ w1s,
                                                const u16* __restrict__ w2s,
                                                const float* __restrict__ b1,
                                                const float* __restrict__ b2,
                                                const float* __restrict__ wtg,
                                                float* __restrict__ out) {
    __shared__ __align__(16) unsigned char smem[67584];
    unsigned char* Hs = smem + 32768;                  // 64 rows x 512B (bf16, swizzled)
    float* wts = (float*)(smem + 65536);               // [E][64]

    const int tid = threadIdx.x;
    const int wid = tid >> 6;                          // 0..7
    const int lane = tid & 63;
    const int l31 = lane & 31;
    const int lg2 = lane >> 5;
    const int tg = wid & 1;                            // 32-tok group
    const int strip = wid >> 1;                        // 0..3: 64h (G1) / 64o (G2) strip
    const int t0 = blockIdx.x * 64;
    const int lfrag = l31 * 16 + lg2 * 8;              // elems into 512-elem frag

    // stage Xs: 64 rows x 512B bf16, swizzle ^((row&15)<<4)
    {
        const float* xb = x + (size_t)t0 * DD;
#pragma unroll
        for (int i = 0; i < 4; ++i) {
            int L = i * 8192 + tid * 16;
            int row = L >> 9, elem = (L & 511) >> 1;
            const float* src = xb + (size_t)row * DD + elem;
            f32x4 a = *(const f32x4*)src;
            f32x4 b = *(const f32x4*)(src + 4);
            u32x4 o;
            o.x = cvt_pk_bf16(a[0], a[1]); o.y = cvt_pk_bf16(a[2], a[3]);
            o.z = cvt_pk_bf16(b[0], b[1]); o.w = cvt_pk_bf16(b[2], b[3]);
            *(u32x4*)(smem + (L ^ ((row & 15) << 4))) = o;
        }
    }
    wts[tid] = wtg[(size_t)(tid >> 6) * TT + t0 + (tid & 63)];
    __syncthreads();

    f32x16 oacc[2];
    oacc[0] = (f32x16)0.0f;
    oacc[1] = (f32x16)0.0f;

    // lane addressing: this wave touches only rows (tokens) tg*32 + l31, 512B rows
    const int xrow = tg * 32 + l31;
    const int xb0 = xrow * 512 + lg2 * 16;
    const int xsz = (xrow & 15) << 4;

#pragma unroll 1
    for (int c = 0; c < 16; ++c) {
        const int e = c >> 1;
        // ---- G1: hf0/hf1 = W1[64h strip] x X[32 tok], K=256 (16 ks), paired W tiles
        {
            f32x16 hf0 = (f32x16)0.0f, hf1 = (f32x16)0.0f;
            const u16* w1p0 = w1s + ((size_t)((c * 8 + strip * 2 + 0) * 16)) * 512 + lfrag;
            const u16* w1p1 = w1s + ((size_t)((c * 8 + strip * 2 + 1) * 16)) * 512 + lfrag;
            bf16x8 A0[2], A1[2];
            A0[0] = ld_frag(w1p0);       A0[1] = ld_frag(w1p0 + 512);
            A1[0] = ld_frag(w1p1);       A1[1] = ld_frag(w1p1 + 512);
#pragma unroll 4
            for (int ks = 0; ks < 16; ++ks) {
                bf16x8 ac0 = A0[ks & 1], ac1 = A1[ks & 1];
                if (ks < 14) {
                    A0[ks & 1] = ld_frag(w1p0 + (ks + 2) * 512);
                    A1[ks & 1] = ld_frag(w1p1 + (ks + 2) * 512);
                }
                bf16x8 b = ld_frag(smem + ((xb0 + ks * 32) ^ xsz));
                hf0 = __builtin_amdgcn_mfma_f32_32x32x16_bf16(ac0, b, hf0, 0, 0, 0);
                hf1 = __builtin_amdgcn_mfma_f32_32x32x16_bf16(ac1, b, hf1, 0, 0, 0);
            }
            // epilogue: +b1, gelu, *wgt, pack -> Hs rows = tok (512B, swizzled)
            float wgt = wts[e * 64 + xrow];
#pragma unroll
            for (int t = 0; t < 2; ++t) {
                const float* b1p = b1 + c * 256 + strip * 64 + t * 32 + lg2 * 4;
                const f32x16& hf = t ? hf1 : hf0;
#pragma unroll
                for (int q = 0; q < 4; ++q) {
                    f32x4 bb = *(const f32x4*)(b1p + q * 8);
                    float g[4];
#pragma unroll
                    for (int r = 0; r < 4; ++r)
                        g[r] = gelu_fast(hf[q * 4 + r] + bb[r]) * wgt;
                    u32x2 pk;
                    pk.x = cvt_pk_bf16(g[0], g[1]);
                    pk.y = cvt_pk_bf16(g[2], g[3]);
                    int hb = (strip * 64 + t * 32 + q * 8 + lg2 * 4) * 2;  // byte in 512B row
                    *(u32x2*)(Hs + ((xrow * 512 + hb) ^ xsz)) = pk;
                }
            }
        }
        __syncthreads();
        // ---- G2: oacc[n] += Hs[32 tok] x W2[64o strip], K=256 (16 ks), paired W tiles
        {
            const u16* w2p0 = w2s + ((size_t)((strip * 2 + 0) * 256 + c * 16)) * 512 + lfrag;
            const u16* w2p1 = w2s + ((size_t)((strip * 2 + 1) * 256 + c * 16)) * 512 + lfrag;
            bf16x8 B0[2], B1[2];
            B0[0] = ld_frag(w2p0);       B0[1] = ld_frag(w2p0 + 512);
            B1[0] = ld_frag(w2p1);       B1[1] = ld_frag(w2p1 + 512);
#pragma unroll 4
            for (int ks = 0; ks < 16; ++ks) {
                bf16x8 bc0 = B0[ks & 1], bc1 = B1[ks & 1];
                if (ks < 14) {
                    B0[ks & 1] = ld_frag(w2p0 + (ks + 2) * 512);
                    B1[ks & 1] = ld_frag(w2p1 + (ks + 2) * 512);
                }
                bf16x8 Ah = ld_frag(Hs + ((xb0 + ks * 32) ^ xsz));
                oacc[0] = __builtin_amdgcn_mfma_f32_32x32x16_bf16(Ah, bc0, oacc[0], 0, 0, 0);
                oacc[1] = __builtin_amdgcn_mfma_f32_32x32x16_bf16(Ah, bc1, oacc[1], 0, 0, 0);
            }
        }
        __syncthreads();
    }

    // epilogue: add sum_e wts[e][tok]*b2[e][o], store. o = strip*64 + n*32 + l31, tok in tg's group.
#pragma unroll
    for (int n = 0; n < 2; ++n) {
        int o = strip * 64 + n * 32 + l31;
        float b2v[EE];
#pragma unroll
        for (int e = 0; e < EE; ++e) b2v[e] = b2[e * OO + o];
#pragma unroll
        for (int r = 0; r < 16; ++r) {
            int tok = tg * 32 + (r & 3) + 8 * (r >> 2) + 4 * lg2;
            float wb = 0.f;
#pragma unroll
            for (int e = 0; e < EE; ++e) wb += wts[e * 64 + tok] * b2v[e];
            out[(size_t)(t0 + tok) * OO + o] = oacc[n][r] + wb;
        }
    }
}

extern "C" void kernel_launch(void* const* d_in, const int* in_sizes, int n_in,
                              void* d_out, int out_size, void* d_ws, size_t ws_size,
                              hipStream_t stream) {
    const float* x  = (const float*)d_in[0];
    const float* gw = (const float*)d_in[1];
    const float* gb = (const float*)d_in[2];
    const float* w1 = (const float*)d_in[3];
    const float* b1 = (const float*)d_in[4];
    const float* w2 = (const float*)d_in[5];
    const float* b2 = (const float*)d_in[6];
    float* out = (float*)d_out;

    char* ws = (char*)d_ws;
    u16* w1s    = (u16*)(ws);                    // 2 MB
    u16* w2s    = (u16*)(ws + 2097152);          // 2 MB
    float* wt   = (float*)(ws + 4194304);        // 2 MB ([E][T])
    double* prt = (double*)(ws + 6291456);       // 2 KB

    k_conv_w1<<<(EE * HH * DD) / 256, 256, 0, stream>>>(w1, w1s);
    k_conv_w2<<<(OO * NN) / 256, 256, 0, stream>>>(w2, w2s);
    k_gating<<<TT / 256, 256, 0, stream>>>(x, gw, gb, wt, prt);
    k_moe<<<TT / 64, 512, 0, stream>>>(x, w1s, w2s, b1, b2, wt, out);
    k_final<<<1, 256, 0, stream>>>(prt, out + (size_t)TT * OO);
}

// Round 15
// 368.787 us; speedup vs baseline: 1.8929x; 1.2976x over previous
//
#include <hip/hip_runtime.h>
#include <math.h>

#define TT 65536
#define DD 256
#define EE 8
#define HH 512
#define OO 256
#define NN 4096

typedef unsigned int u32;
typedef unsigned short u16;
typedef __attribute__((ext_vector_type(4))) float f32x4;
typedef __attribute__((ext_vector_type(16))) float f32x16;
typedef __attribute__((ext_vector_type(2))) u32 u32x2;
typedef __attribute__((ext_vector_type(4))) u32 u32x4;
typedef __attribute__((ext_vector_type(8))) __bf16 bf16x8;

__device__ __forceinline__ u16 f2bf(float f) {
    u32 u = __builtin_bit_cast(u32, f);
    u32 r = (u + 0x7fffu + ((u >> 16) & 1u)) >> 16;
    return (u16)r;
}

__device__ __forceinline__ u32 cvt_pk_bf16(float lo, float hi) {
    u32 r;
    asm("v_cvt_pk_bf16_f32 %0, %1, %2" : "=v"(r) : "v"(lo), "v"(hi));
    return r;
}

__device__ __forceinline__ bf16x8 ld_frag(const void* p) {
    u32x4 v = *(const u32x4*)p;
    return __builtin_bit_cast(bf16x8, v);
}

__device__ __forceinline__ float gelu_fast(float v) {
    float t = v * v;
    float u = __builtin_fmaf(t, -0.1029479f, -2.3022075f);
    float z = v * u;
    float e = __builtin_amdgcn_exp2f(z);
    return v * __builtin_amdgcn_rcpf(1.0f + e);
}

// ---------------- weight conversions to fragment-major layout ----------------
// w1 [E][D][H] f32 -> w1s [nb=n>>5][kb=k>>4][l=n&31][j=k&15] bf16 (n=e*512+h, k=d)
__global__ __launch_bounds__(256) void k_conv_w1(const float* __restrict__ w1, u16* __restrict__ w1s) {
    int i = blockIdx.x * 256 + threadIdx.x;            // < 1M
    int j = i & 15, l = (i >> 4) & 31, kb = (i >> 9) & 15, nb = i >> 13;
    int n = nb * 32 + l, k = kb * 16 + j;
    int e = n >> 9, h = n & 511;
    w1s[i] = f2bf(w1[(size_t)e * 131072 + (size_t)k * 512 + h]);
}
// w2 [E][H][O] f32 -> w2s [ob=o>>5][kb2=k2>>4][l=o&31][j=k2&15] bf16 (k2=e*512+h)
__global__ __launch_bounds__(256) void k_conv_w2(const float* __restrict__ w2, u16* __restrict__ w2s) {
    int i = blockIdx.x * 256 + threadIdx.x;            // < 1M
    int j = i & 15, l = (i >> 4) & 31, kb2 = (i >> 9) & 255, ob = i >> 17;
    int o = ob * 32 + l, k2 = kb2 * 16 + j;
    int e = k2 >> 9, h = k2 & 511;
    w2s[i] = f2bf(w2[(size_t)e * 131072 + (size_t)h * 256 + o]);
}

// ---------------- gating ----------------
__global__ __launch_bounds__(256) void k_gating(const float* __restrict__ x,
                                                const float* __restrict__ gw,
                                                const float* __restrict__ gb,
                                                float* __restrict__ wt,
                                                double* __restrict__ part) {
    __shared__ float gws[DD * EE];
    __shared__ float gbs[EE];
    __shared__ double red[256];
    int tid = threadIdx.x;
    for (int i = tid; i < DD * EE; i += 256) gws[i] = gw[i];
    if (tid < EE) gbs[tid] = gb[tid];
    __syncthreads();

    int t = blockIdx.x * 256 + tid;
    double l[EE];
#pragma unroll
    for (int e = 0; e < EE; ++e) l[e] = (double)gbs[e];

    const f32x4* xr = (const f32x4*)(x + (size_t)t * DD);
    for (int d4 = 0; d4 < DD / 4; ++d4) {
        f32x4 xv = xr[d4];
#pragma unroll
        for (int j = 0; j < 4; ++j) {
            double xs = (double)xv[j];
            int d = d4 * 4 + j;
#pragma unroll
            for (int e = 0; e < EE; ++e) l[e] += xs * (double)gws[d * EE + e];
        }
    }
    double mx = l[0];
#pragma unroll
    for (int e = 1; e < EE; ++e) mx = l[e] > mx ? l[e] : mx;
    double p[EE], s = 0.0;
#pragma unroll
    for (int e = 0; e < EE; ++e) { p[e] = exp(l[e] - mx); s += p[e]; }
    double inv = 1.0 / s;
    double ent = 0.0;
#pragma unroll
    for (int e = 0; e < EE; ++e) { p[e] *= inv; ent += p[e] * log(p[e] + 1e-8); }

    bool mask[EE];
#pragma unroll
    for (int e = 0; e < EE; ++e) {
        double c = 0.0; int rk = 0;
#pragma unroll
        for (int f = 0; f < EE; ++f) {
            bool before = (p[f] > p[e]) || (p[f] == p[e] && f < e);
            if (before) { c += p[f]; rk++; }
        }
        c += p[e];
        mask[e] = (c <= 0.7) || (rk == 0);
    }
    double ms = 0.0;
#pragma unroll
    for (int e = 0; e < EE; ++e) if (mask[e]) ms += p[e];
    double inv2 = 1.0 / ms;
#pragma unroll
    for (int e = 0; e < EE; ++e) wt[(size_t)e * TT + t] = (float)(mask[e] ? p[e] * inv2 : 0.0);

    red[tid] = -ent;
    __syncthreads();
    for (int st = 128; st > 0; st >>= 1) {
        if (tid < st) red[tid] += red[tid + st];
        __syncthreads();
    }
    if (tid == 0) part[blockIdx.x] = red[0];
}

__global__ __launch_bounds__(256) void k_final(const double* __restrict__ part, float* __restrict__ loss) {
    __shared__ double red[256];
    int tid = threadIdx.x;
    red[tid] = part[tid];
    __syncthreads();
    for (int st = 128; st > 0; st >>= 1) {
        if (tid < st) red[tid] += red[tid + st];
        __syncthreads();
    }
    if (tid == 0) loss[0] = (float)(red[0] / (double)TT);
}

// ---------------- fused MoE MLP (v15 = v12 + setprio) ----------------
// 64 tok/block, 512 thr (8 waves). 16 chunks of 256 h (e = c>>1). Hs single buffer,
// TWO barriers per chunk: { G1(c) -> Hs ; BAR ; G2(c) ; BAR }.
// G1: wave = unique 32h strip (wid) x 64tok: hf[2] (32 acc). Per ks: 1 global A + 2 LDS B -> 2 MFMA.
// G2: wave = unique 32o strip (wid) x 64tok: oacc[2] (32 acc). Per ks: 1 global B + 2 LDS A -> 2 MFMA.
// W1/W2 each read EXACTLY ONCE per block. Depth-4 rotating global prefetch (static indices).
// Acc = 64, VGPR 64 -> unified 128 -> 4 waves/SIMD (2 blocks/CU). LDS 66K.
// v15: s_setprio(1) around MFMA ks-loops (T5) - 2 blocks/CU give cross-block phase
// diversity, so the CU scheduler can favor the MFMA-issuing block's waves.
__global__ __launch_bounds__(512, 4) void k_moe(const float* __restrict__ x,
                                                const u16* __restrict__ w1s,
                                                const u16* __restrict__ w2s,
                                                const float* __restrict__ b1,
                                                const float* __restrict__ b2,
                                                const float* __restrict__ wtg,
                                                float* __restrict__ out) {
    __shared__ __align__(16) unsigned char smem[67584];
    unsigned char* Hs = smem + 32768;
    float* wts = (float*)(smem + 65536);               // [E][64]

    const int tid = threadIdx.x;
    const int wid = tid >> 6;
    const int lane = tid & 63;
    const int l31 = lane & 31;
    const int lg2 = lane >> 5;
    const int t0 = blockIdx.x * 64;
    const int lfrag = l31 * 16 + lg2 * 8;              // elems into 512-elem frag

    // stage Xs: 64 rows x 512B bf16, swizzle ^((row&15)<<4)
    {
        const float* xb = x + (size_t)t0 * DD;
#pragma unroll
        for (int i = 0; i < 4; ++i) {
            int L = i * 8192 + tid * 16;
            int row = L >> 9, elem = (L & 511) >> 1;
            const float* src = xb + (size_t)row * DD + elem;
            f32x4 a = *(const f32x4*)src;
            f32x4 b = *(const f32x4*)(src + 4);
            u32x4 o;
            o.x = cvt_pk_bf16(a[0], a[1]); o.y = cvt_pk_bf16(a[2], a[3]);
            o.z = cvt_pk_bf16(b[0], b[1]); o.w = cvt_pk_bf16(b[2], b[3]);
            *(u32x4*)(smem + (L ^ ((row & 15) << 4))) = o;
        }
    }
    wts[tid] = wtg[(size_t)(tid >> 6) * TT + t0 + (tid & 63)];
    __syncthreads();

    f32x16 oacc[2];
    oacc[0] = (f32x16)0.0f;
    oacc[1] = (f32x16)0.0f;

    // lane addressing constants: both G1-B (Xs) and G2-A (Hs) use rows tokA/tokB, 512B rows
    const int tokA = l31, tokB = 32 + l31;
    const int rbA = tokA * 512 + lg2 * 16, rszA = (tokA & 15) << 4;
    const int rbB = tokB * 512 + lg2 * 16, rszB = (tokB & 15) << 4;

#pragma unroll 1
    for (int c = 0; c < 16; ++c) {
        const int e = c >> 1;
        // ---- G1: hf[t] = W1[strip wid] x X[64 tok], K=256 (16 ks), depth-4 prefetch
        {
            f32x16 hf0 = (f32x16)0.0f, hf1 = (f32x16)0.0f;
            const u16* w1p = w1s + ((size_t)((c * 8 + wid) * 16)) * 512 + lfrag;
            bf16x8 A[4];
            A[0] = ld_frag(w1p);
            A[1] = ld_frag(w1p + 512);
            A[2] = ld_frag(w1p + 1024);
            A[3] = ld_frag(w1p + 1536);
            __builtin_amdgcn_s_setprio(1);
#pragma unroll 4
            for (int ks = 0; ks < 16; ++ks) {
                bf16x8 ac = A[ks & 3];
                if (ks < 12) A[ks & 3] = ld_frag(w1p + (ks + 4) * 512);
                bf16x8 b0 = ld_frag(smem + ((rbA + ks * 32) ^ rszA));
                bf16x8 b1 = ld_frag(smem + ((rbB + ks * 32) ^ rszB));
                hf0 = __builtin_amdgcn_mfma_f32_32x32x16_bf16(ac, b0, hf0, 0, 0, 0);
                hf1 = __builtin_amdgcn_mfma_f32_32x32x16_bf16(ac, b1, hf1, 0, 0, 0);
            }
            __builtin_amdgcn_s_setprio(0);
            // epilogue: +b1, gelu, *wgt, pack -> Hs (rows tok, 512B, swizzled); h-cols wid*32..+32
            const float* b1p = b1 + c * 256 + wid * 32 + lg2 * 4;
            float wgtA = wts[e * 64 + tokA];
            float wgtB = wts[e * 64 + tokB];
#pragma unroll
            for (int q = 0; q < 4; ++q) {
                f32x4 bb = *(const f32x4*)(b1p + q * 8);
                float g0[4], g1[4];
#pragma unroll
                for (int r = 0; r < 4; ++r) {
                    g0[r] = gelu_fast(hf0[q * 4 + r] + bb[r]) * wgtA;
                    g1[r] = gelu_fast(hf1[q * 4 + r] + bb[r]) * wgtB;
                }
                u32x2 pk0, pk1;
                pk0.x = cvt_pk_bf16(g0[0], g0[1]); pk0.y = cvt_pk_bf16(g0[2], g0[3]);
                pk1.x = cvt_pk_bf16(g1[0], g1[1]); pk1.y = cvt_pk_bf16(g1[2], g1[3]);
                int hb = (wid * 32 + q * 8 + lg2 * 4) * 2;     // byte offset of h within 512B row
                *(u32x2*)(Hs + ((tokA * 512 + hb) ^ rszA)) = pk0;
                *(u32x2*)(Hs + ((tokB * 512 + hb) ^ rszB)) = pk1;
            }
        }
        __syncthreads();
        // ---- G2: oacc[m] += Hs[64 tok] x W2[strip wid], K=256 (16 ks), depth-4 prefetch
        {
            const u16* w2p = w2s + ((size_t)(wid * 256 + c * 16)) * 512 + lfrag;
            bf16x8 B[4];
            B[0] = ld_frag(w2p);
            B[1] = ld_frag(w2p + 512);
            B[2] = ld_frag(w2p + 1024);
            B[3] = ld_frag(w2p + 1536);
            __builtin_amdgcn_s_setprio(1);
#pragma unroll 4
            for (int ks = 0; ks < 16; ++ks) {
                bf16x8 bc = B[ks & 3];
                if (ks < 12) B[ks & 3] = ld_frag(w2p + (ks + 4) * 512);
                bf16x8 A0 = ld_frag(Hs + ((rbA + ks * 32) ^ rszA));
                bf16x8 A1 = ld_frag(Hs + ((rbB + ks * 32) ^ rszB));
                oacc[0] = __builtin_amdgcn_mfma_f32_32x32x16_bf16(A0, bc, oacc[0], 0, 0, 0);
                oacc[1] = __builtin_amdgcn_mfma_f32_32x32x16_bf16(A1, bc, oacc[1], 0, 0, 0);
            }
            __builtin_amdgcn_s_setprio(0);
        }
        __syncthreads();
    }

    // epilogue: add sum_e wts[e][tok]*b2[e][o], store. o = wid*32 + l31.
    {
        int o = wid * 32 + l31;
        float b2v[EE];
#pragma unroll
        for (int e = 0; e < EE; ++e) b2v[e] = b2[e * OO + o];
#pragma unroll
        for (int m = 0; m < 2; ++m) {
#pragma unroll
            for (int r = 0; r < 16; ++r) {
                int tok = m * 32 + (r & 3) + 8 * (r >> 2) + 4 * lg2;
                float wb = 0.f;
#pragma unroll
                for (int e = 0; e < EE; ++e) wb += wts[e * 64 + tok] * b2v[e];
                out[(size_t)(t0 + tok) * OO + o] = oacc[m][r] + wb;
            }
        }
    }
}

extern "C" void kernel_launch(void* const* d_in, const int* in_sizes, int n_in,
                              void* d_out, int out_size, void* d_ws, size_t ws_size,
                              hipStream_t stream) {
    const float* x  = (const float*)d_in[0];
    const float* gw = (const float*)d_in[1];
    const float* gb = (const float*)d_in[2];
    const float* w1 = (const float*)d_in[3];
    const float* b1 = (const float*)d_in[4];
    const float* w2 = (const float*)d_in[5];
    const float* b2 = (const float*)d_in[6];
    float* out = (float*)d_out;

    char* ws = (char*)d_ws;
    u16* w1s    = (u16*)(ws);                    // 2 MB
    u16* w2s    = (u16*)(ws + 2097152);          // 2 MB
    float* wt   = (float*)(ws + 4194304);        // 2 MB ([E][T])
    double* prt = (double*)(ws + 6291456);       // 2 KB

    k_conv_w1<<<(EE * HH * DD) / 256, 256, 0, stream>>>(w1, w1s);
    k_conv_w2<<<(OO * NN) / 256, 256, 0, stream>>>(w2, w2s);
    k_gating<<<TT / 256, 256, 0, stream>>>(x, gw, gb, wt, prt);
    k_moe<<<TT / 64, 512, 0, stream>>>(x, w1s, w2s, b1, b2, wt, out);
    k_final<<<1, 256, 0, stream>>>(prt, out + (size_t)TT * OO);
}

// Round 16
// 322.116 us; speedup vs baseline: 2.1672x; 1.1449x over previous
//
#include <hip/hip_runtime.h>
#include <math.h>

#define TT 65536
#define DD 256
#define EE 8
#define HH 512
#define OO 256
#define NN 4096

typedef unsigned int u32;
typedef unsigned short u16;
typedef __attribute__((ext_vector_type(4))) float f32x4;
typedef __attribute__((ext_vector_type(16))) float f32x16;
typedef __attribute__((ext_vector_type(2))) u32 u32x2;
typedef __attribute__((ext_vector_type(4))) u32 u32x4;
typedef __attribute__((ext_vector_type(8))) __bf16 bf16x8;

__device__ __forceinline__ u16 f2bf(float f) {
    u32 u = __builtin_bit_cast(u32, f);
    u32 r = (u + 0x7fffu + ((u >> 16) & 1u)) >> 16;
    return (u16)r;
}

__device__ __forceinline__ u32 cvt_pk_bf16(float lo, float hi) {
    u32 r;
    asm("v_cvt_pk_bf16_f32 %0, %1, %2" : "=v"(r) : "v"(lo), "v"(hi));
    return r;
}

__device__ __forceinline__ bf16x8 ld_frag(const void* p) {
    u32x4 v = *(const u32x4*)p;
    return __builtin_bit_cast(bf16x8, v);
}

__device__ __forceinline__ float gelu_fast(float v) {
    float t = v * v;
    float u = __builtin_fmaf(t, -0.1029479f, -2.3022075f);
    float z = v * u;
    float e = __builtin_amdgcn_exp2f(z);
    return v * __builtin_amdgcn_rcpf(1.0f + e);
}

// ---------------- weight conversions to fragment-major layout ----------------
__global__ __launch_bounds__(256) void k_conv_w1(const float* __restrict__ w1, u16* __restrict__ w1s) {
    int i = blockIdx.x * 256 + threadIdx.x;            // < 1M
    int j = i & 15, l = (i >> 4) & 31, kb = (i >> 9) & 15, nb = i >> 13;
    int n = nb * 32 + l, k = kb * 16 + j;
    int e = n >> 9, h = n & 511;
    w1s[i] = f2bf(w1[(size_t)e * 131072 + (size_t)k * 512 + h]);
}
__global__ __launch_bounds__(256) void k_conv_w2(const float* __restrict__ w2, u16* __restrict__ w2s) {
    int i = blockIdx.x * 256 + threadIdx.x;            // < 1M
    int j = i & 15, l = (i >> 4) & 31, kb2 = (i >> 9) & 255, ob = i >> 17;
    int o = ob * 32 + l, k2 = kb2 * 16 + j;
    int e = k2 >> 9, h = k2 & 511;
    w2s[i] = f2bf(w2[(size_t)e * 131072 + (size_t)h * 256 + o]);
}

// ---------------- gating: softmax, entropy, top-p, mask-bin rank ----------------
__global__ __launch_bounds__(256) void k_gating(const float* __restrict__ x,
                                                const float* __restrict__ gw,
                                                const float* __restrict__ gb,
                                                float* __restrict__ wt,
                                                double* __restrict__ part,
                                                u32* __restrict__ maskA,
                                                u32* __restrict__ rank,
                                                u32* __restrict__ bins) {
    __shared__ float gws[DD * EE];
    __shared__ float gbs[EE];
    __shared__ double red[256];
    int tid = threadIdx.x;
    for (int i = tid; i < DD * EE; i += 256) gws[i] = gw[i];
    if (tid < EE) gbs[tid] = gb[tid];
    __syncthreads();

    int t = blockIdx.x * 256 + tid;
    double l[EE];
#pragma unroll
    for (int e = 0; e < EE; ++e) l[e] = (double)gbs[e];

    const f32x4* xr = (const f32x4*)(x + (size_t)t * DD);
    for (int d4 = 0; d4 < DD / 4; ++d4) {
        f32x4 xv = xr[d4];
#pragma unroll
        for (int j = 0; j < 4; ++j) {
            double xs = (double)xv[j];
            int d = d4 * 4 + j;
#pragma unroll
            for (int e = 0; e < EE; ++e) l[e] += xs * (double)gws[d * EE + e];
        }
    }
    double mx = l[0];
#pragma unroll
    for (int e = 1; e < EE; ++e) mx = l[e] > mx ? l[e] : mx;
    double p[EE], s = 0.0;
#pragma unroll
    for (int e = 0; e < EE; ++e) { p[e] = exp(l[e] - mx); s += p[e]; }
    double inv = 1.0 / s;
    double ent = 0.0;
#pragma unroll
    for (int e = 0; e < EE; ++e) { p[e] *= inv; ent += p[e] * log(p[e] + 1e-8); }

    bool mask[EE];
#pragma unroll
    for (int e = 0; e < EE; ++e) {
        double c = 0.0; int rk = 0;
#pragma unroll
        for (int f = 0; f < EE; ++f) {
            bool before = (p[f] > p[e]) || (p[f] == p[e] && f < e);
            if (before) { c += p[f]; rk++; }
        }
        c += p[e];
        mask[e] = (c <= 0.7) || (rk == 0);
    }
    double ms = 0.0;
#pragma unroll
    for (int e = 0; e < EE; ++e) if (mask[e]) ms += p[e];
    double inv2 = 1.0 / ms;
    u32 m = 0;
#pragma unroll
    for (int e = 0; e < EE; ++e) {
        wt[(size_t)e * TT + t] = (float)(mask[e] ? p[e] * inv2 : 0.0);
        if (mask[e]) m |= (1u << e);
    }
    maskA[t] = m;
    rank[t] = atomicAdd(&bins[m], 1u);

    red[tid] = -ent;
    __syncthreads();
    for (int st = 128; st > 0; st >>= 1) {
        if (tid < st) red[tid] += red[tid + st];
        __syncthreads();
    }
    if (tid == 0) part[blockIdx.x] = red[0];
}

// exclusive prefix sum of 256 bins
__global__ __launch_bounds__(256) void k_scan(const u32* __restrict__ bins, u32* __restrict__ base) {
    __shared__ u32 s[256];
    int t = threadIdx.x;
    u32 mine = bins[t];
    s[t] = mine;
    __syncthreads();
    for (int off = 1; off < 256; off <<= 1) {
        u32 v = (t >= off) ? s[t - off] : 0u;
        __syncthreads();
        s[t] += v;
        __syncthreads();
    }
    base[t] = s[t] - mine;
}

__global__ __launch_bounds__(256) void k_scatter(const u32* __restrict__ maskA,
                                                 const u32* __restrict__ rank,
                                                 const u32* __restrict__ base,
                                                 u32* __restrict__ idx) {
    int t = blockIdx.x * 256 + threadIdx.x;
    idx[base[maskA[t]] + rank[t]] = (u32)t;
}

__global__ __launch_bounds__(256) void k_final(const double* __restrict__ part, float* __restrict__ loss) {
    __shared__ double red[256];
    int tid = threadIdx.x;
    red[tid] = part[tid];
    __syncthreads();
    for (int st = 128; st > 0; st >>= 1) {
        if (tid < st) red[tid] += red[tid + st];
        __syncthreads();
    }
    if (tid == 0) loss[0] = (float)(red[0] / (double)TT);
}

// ---------------- fused MoE MLP (v16 = v15 + mask-sorted expert skipping) ----------------
// Tokens pre-sorted by expert-mask; block processes 64 gathered tokens, skips experts
// with zero weight across the whole block (mask-pure blocks skip ~35% of chunks).
// Geometry identical to v12/v15: 512 thr, 16 chunks of 256h, unique 32h/32o strips,
// depth-4 weight prefetch, acc=64, VGPR~64 -> 4 waves/SIMD, LDS 66.5K -> 2 blocks/CU.
__global__ __launch_bounds__(512, 4) void k_moe(const float* __restrict__ x,
                                                const u16* __restrict__ w1s,
                                                const u16* __restrict__ w2s,
                                                const float* __restrict__ b1,
                                                const float* __restrict__ b2,
                                                const float* __restrict__ wtg,
                                                const u32* __restrict__ idxg,
                                                float* __restrict__ out) {
    __shared__ __align__(16) unsigned char smem[68096];
    unsigned char* Hs = smem + 32768;
    float* wts = (float*)(smem + 65536);               // [E][64] = 2K
    u32* idxS  = (u32*)(smem + 67584);                 // 64 token ids
    u32* actS  = (u32*)(smem + 67840);                 // 8 expert-active flags

    const int tid = threadIdx.x;
    const int wid = tid >> 6;
    const int lane = tid & 63;
    const int l31 = lane & 31;
    const int lg2 = lane >> 5;
    const int lfrag = l31 * 16 + lg2 * 8;              // elems into 512-elem frag

    if (tid < 64) idxS[tid] = idxg[blockIdx.x * 64 + tid];
    __syncthreads();

    // stage Xs (gathered rows): 64 rows x 512B bf16, swizzle ^((row&15)<<4)
#pragma unroll
    for (int i = 0; i < 4; ++i) {
        int L = i * 8192 + tid * 16;
        int row = L >> 9, elem = (L & 511) >> 1;
        const float* src = x + (size_t)idxS[row] * DD + elem;
        f32x4 a = *(const f32x4*)src;
        f32x4 b = *(const f32x4*)(src + 4);
        u32x4 o;
        o.x = cvt_pk_bf16(a[0], a[1]); o.y = cvt_pk_bf16(a[2], a[3]);
        o.z = cvt_pk_bf16(b[0], b[1]); o.w = cvt_pk_bf16(b[2], b[3]);
        *(u32x4*)(smem + (L ^ ((row & 15) << 4))) = o;
    }
    // gathered token weights: wts[e][l], e = tid>>6, l = tid&63
    wts[tid] = wtg[(size_t)wid * TT + idxS[lane]];
    __syncthreads();
    // per-expert block-active flag (wave wid handles expert wid)
    {
        int av = __any(wts[tid] != 0.0f);
        if (lane == 0) actS[wid] = (u32)(av != 0);
    }
    __syncthreads();

    f32x16 oacc[2];
    oacc[0] = (f32x16)0.0f;
    oacc[1] = (f32x16)0.0f;

    const int tokA = l31, tokB = 32 + l31;
    const int rbA = tokA * 512 + lg2 * 16, rszA = (tokA & 15) << 4;
    const int rbB = tokB * 512 + lg2 * 16, rszB = (tokB & 15) << 4;

#pragma unroll 1
    for (int c = 0; c < 16; ++c) {
        const int e = c >> 1;
        if (!actS[e]) continue;                        // block-uniform skip
        // ---- G1: hf[t] = W1[strip wid] x X[64 tok], K=256 (16 ks), depth-4 prefetch
        {
            f32x16 hf0 = (f32x16)0.0f, hf1 = (f32x16)0.0f;
            const u16* w1p = w1s + ((size_t)((c * 8 + wid) * 16)) * 512 + lfrag;
            bf16x8 A[4];
            A[0] = ld_frag(w1p);
            A[1] = ld_frag(w1p + 512);
            A[2] = ld_frag(w1p + 1024);
            A[3] = ld_frag(w1p + 1536);
            __builtin_amdgcn_s_setprio(1);
#pragma unroll 4
            for (int ks = 0; ks < 16; ++ks) {
                bf16x8 ac = A[ks & 3];
                if (ks < 12) A[ks & 3] = ld_frag(w1p + (ks + 4) * 512);
                bf16x8 b0 = ld_frag(smem + ((rbA + ks * 32) ^ rszA));
                bf16x8 b1 = ld_frag(smem + ((rbB + ks * 32) ^ rszB));
                hf0 = __builtin_amdgcn_mfma_f32_32x32x16_bf16(ac, b0, hf0, 0, 0, 0);
                hf1 = __builtin_amdgcn_mfma_f32_32x32x16_bf16(ac, b1, hf1, 0, 0, 0);
            }
            __builtin_amdgcn_s_setprio(0);
            // epilogue: +b1, gelu, *wgt, pack -> Hs (rows tok, 512B, swizzled)
            const float* b1p = b1 + c * 256 + wid * 32 + lg2 * 4;
            float wgtA = wts[e * 64 + tokA];
            float wgtB = wts[e * 64 + tokB];
#pragma unroll
            for (int q = 0; q < 4; ++q) {
                f32x4 bb = *(const f32x4*)(b1p + q * 8);
                float g0[4], g1[4];
#pragma unroll
                for (int r = 0; r < 4; ++r) {
                    g0[r] = gelu_fast(hf0[q * 4 + r] + bb[r]) * wgtA;
                    g1[r] = gelu_fast(hf1[q * 4 + r] + bb[r]) * wgtB;
                }
                u32x2 pk0, pk1;
                pk0.x = cvt_pk_bf16(g0[0], g0[1]); pk0.y = cvt_pk_bf16(g0[2], g0[3]);
                pk1.x = cvt_pk_bf16(g1[0], g1[1]); pk1.y = cvt_pk_bf16(g1[2], g1[3]);
                int hb = (wid * 32 + q * 8 + lg2 * 4) * 2;
                *(u32x2*)(Hs + ((tokA * 512 + hb) ^ rszA)) = pk0;
                *(u32x2*)(Hs + ((tokB * 512 + hb) ^ rszB)) = pk1;
            }
        }
        __syncthreads();
        // ---- G2: oacc[m] += Hs[64 tok] x W2[strip wid], K=256 (16 ks), depth-4 prefetch
        {
            const u16* w2p = w2s + ((size_t)(wid * 256 + c * 16)) * 512 + lfrag;
            bf16x8 B[4];
            B[0] = ld_frag(w2p);
            B[1] = ld_frag(w2p + 512);
            B[2] = ld_frag(w2p + 1024);
            B[3] = ld_frag(w2p + 1536);
            __builtin_amdgcn_s_setprio(1);
#pragma unroll 4
            for (int ks = 0; ks < 16; ++ks) {
                bf16x8 bc = B[ks & 3];
                if (ks < 12) B[ks & 3] = ld_frag(w2p + (ks + 4) * 512);
                bf16x8 A0 = ld_frag(Hs + ((rbA + ks * 32) ^ rszA));
                bf16x8 A1 = ld_frag(Hs + ((rbB + ks * 32) ^ rszB));
                oacc[0] = __builtin_amdgcn_mfma_f32_32x32x16_bf16(A0, bc, oacc[0], 0, 0, 0);
                oacc[1] = __builtin_amdgcn_mfma_f32_32x32x16_bf16(A1, bc, oacc[1], 0, 0, 0);
            }
            __builtin_amdgcn_s_setprio(0);
        }
        __syncthreads();
    }

    // epilogue: add sum_e wts[e][tok]*b2[e][o], scatter-store by original token id
    {
        int o = wid * 32 + l31;
        float b2v[EE];
#pragma unroll
        for (int e = 0; e < EE; ++e) b2v[e] = b2[e * OO + o];
#pragma unroll
        for (int m = 0; m < 2; ++m) {
#pragma unroll
            for (int r = 0; r < 16; ++r) {
                int tok = m * 32 + (r & 3) + 8 * (r >> 2) + 4 * lg2;
                float wb = 0.f;
#pragma unroll
                for (int e = 0; e < EE; ++e) wb += wts[e * 64 + tok] * b2v[e];
                out[(size_t)idxS[tok] * OO + o] = oacc[m][r] + wb;
            }
        }
    }
}

extern "C" void kernel_launch(void* const* d_in, const int* in_sizes, int n_in,
                              void* d_out, int out_size, void* d_ws, size_t ws_size,
                              hipStream_t stream) {
    const float* x  = (const float*)d_in[0];
    const float* gw = (const float*)d_in[1];
    const float* gb = (const float*)d_in[2];
    const float* w1 = (const float*)d_in[3];
    const float* b1 = (const float*)d_in[4];
    const float* w2 = (const float*)d_in[5];
    const float* b2 = (const float*)d_in[6];
    float* out = (float*)d_out;

    char* ws = (char*)d_ws;
    u16* w1s    = (u16*)(ws);                    // 2 MB
    u16* w2s    = (u16*)(ws + 2097152);          // 2 MB
    float* wt   = (float*)(ws + 4194304);        // 2 MB ([E][T])
    double* prt = (double*)(ws + 6291456);       // 2 KB
    u32* bins   = (u32*)(ws + 6295552);          // 1 KB
    u32* base   = (u32*)(ws + 6299648);          // 1 KB
    u32* maskA  = (u32*)(ws + 6307840);          // 256 KB
    u32* rank   = (u32*)(ws + 6569984);          // 256 KB
    u32* idx    = (u32*)(ws + 6832128);          // 256 KB

    hipMemsetAsync(bins, 0, 1024, stream);
    k_conv_w1<<<(EE * HH * DD) / 256, 256, 0, stream>>>(w1, w1s);
    k_conv_w2<<<(OO * NN) / 256, 256, 0, stream>>>(w2, w2s);
    k_gating<<<TT / 256, 256, 0, stream>>>(x, gw, gb, wt, prt, maskA, rank, bins);
    k_scan<<<1, 256, 0, stream>>>(bins, base);
    k_scatter<<<TT / 256, 256, 0, stream>>>(maskA, rank, base, idx);
    k_moe<<<TT / 64, 512, 0, stream>>>(x, w1s, w2s, b1, b2, wt, idx, out);
    k_final<<<1, 256, 0, stream>>>(prt, out + (size_t)TT * OO);
}